// Round 4
// baseline (329.898 us; speedup 1.0000x reference)
//
#include <hip/hip_runtime.h>
#include <math.h>

#define NB   8
#define NC   256
#define NH   80
#define NW   80
#define NHW  6400
#define GN_EPS 1e-5f

typedef __bf16 bf16;
typedef bf16 bf16x2 __attribute__((ext_vector_type(2)));
typedef bf16 bf16x4 __attribute__((ext_vector_type(4)));
typedef bf16 bf16x8 __attribute__((ext_vector_type(8)));
typedef float f32x4 __attribute__((ext_vector_type(4)));

typedef __attribute__((address_space(1))) void gvoid;
typedef __attribute__((address_space(3))) void lvoid;
__device__ __forceinline__ void glds16(const void* g, void* l) {
    __builtin_amdgcn_global_load_lds((const gvoid*)g, (lvoid*)l, 16, 0, 0);
}

// Aw: [9 tap][4 qq] qq stride 520 elems (1040 B -> bank offset +4)
#define AW_Q 520
#define AW_T 2080
#define AW_BUF 18720   // 9 * 2080 elems per buffer (37440 B)

// ---------------- setup: zero stats, repack both weight tensors ------------------
// wA layout: [chunk(8)][tap(9)][qq(4)][co(256)][c8(8)] bf16
__global__ __launch_bounds__(256) void setup_kernel(
    const float* __restrict__ w1, const float* __restrict__ w2,
    bf16* __restrict__ wA1, bf16* __restrict__ wA2,
    float* __restrict__ stats)
{
    int blk = blockIdx.x, tid = threadIdx.x;
    if (blk == 0) {
        #pragma unroll
        for (int k = 0; k < 8; k++) stats[tid + k * 256] = 0.0f;
        return;
    }
    int rb = blk - 1;                            // 0..4607
    const float* w = (rb < 2304) ? w1 : w2;
    bf16* wA       = (rb < 2304) ? wA1 : wA2;
    int idx = (rb % 2304) * 256 + tid;
    int c8 = idx & 7;
    int co = (idx >> 3) & 255;
    int qq = (idx >> 11) & 3;
    int tc = idx >> 13;                          // 0..71
    int tap = tc % 9, chunk = tc / 9;
    int ci = chunk * 32 + qq * 8 + c8;
    wA[idx] = (bf16)w[(size_t)(co * 256 + ci) * 9 + tap];
}

// ---------------- prep1: x NCHW f32 -> xp[b][cib][82][82][8] bf16 + halo + gate part
__global__ __launch_bounds__(256) void prep1_kernel(
    const float* __restrict__ x, bf16* __restrict__ xp,
    const float* __restrict__ gw, float* __restrict__ gpart)
{
    __shared__ float tile[8 * 84];
    int bid = blockIdx.x;
    int row = bid % 80;
    int cib = (bid / 80) & 31;
    int b   = bid / 2560;
    for (int e = threadIdx.x; e < 640; e += 256) {
        int c8 = e / 80, col = e - c8 * 80;
        tile[c8 * 84 + col] = x[((size_t)(b * NC + cib * 8 + c8) * NH + row) * NW + col];
    }
    __syncthreads();
    // interior pack
    size_t base = (((size_t)(b * 32 + cib) * 82 + row + 1) * 82) * 8 + 8;
    for (int t = threadIdx.x; t < 320; t += 256) {
        int e = 2 * t, col = e >> 3, c8 = e & 7;
        bf16x2 pk = { (bf16)tile[c8 * 84 + col], (bf16)tile[(c8 + 1) * 84 + col] };
        *(bf16x2*)(xp + base + e) = pk;
    }
    // gate partial over this block's 8 channels -> per-cib slice (no atomics)
    if (threadIdx.x < 80) {
        int col = threadIdx.x;
        float s = 0.0f;
        #pragma unroll
        for (int c8 = 0; c8 < 8; c8++) s = fmaf(tile[c8 * 84 + col], gw[cib * 8 + c8], s);
        gpart[((size_t)cib * NB + b) * NHW + row * 80 + col] = s;
    }
    // halo zeroing
    const uint4 z4 = make_uint4(0u, 0u, 0u, 0u);
    size_t img = ((size_t)(b * 32 + cib)) * 82;
    if (threadIdx.x < 2) {
        int col = threadIdx.x * 81;
        *(uint4*)(xp + ((img + row + 1) * 82 + col) * 8) = z4;
    }
    if (row == 0 || row == 79) {
        int prow = (row == 0) ? 0 : 81;
        for (int u = threadIdx.x; u < 82; u += 256)
            *(uint4*)(xp + ((img + prow) * 82 + u) * 8) = z4;
    }
}

// ---------------- gate finalize: sum 32 partials, g = relu(tanh(s + b)) ---------
__global__ __launch_bounds__(256) void gate_fin_kernel(
    const float* __restrict__ gpart, const float* __restrict__ gb,
    float* __restrict__ gate)
{
    int i = blockIdx.x * 256 + threadIdx.x;      // b*NHW + p, 51200 total
    float s = gb[0];
    #pragma unroll 8
    for (int k = 0; k < 32; k++) s += gpart[(size_t)k * (NB * NHW) + i];
    gate[i] = fmaxf(tanhf(s), 0.0f);
}

// ---------------- conv: implicit GEMM; A (weights) via dbuf LDS, B direct global -
// block = 64co x 5rows x 80px, 5 waves (wave = one output row)
__global__ __launch_bounds__(320, 3) void conv_kernel(
    const bf16* __restrict__ xp, const bf16* __restrict__ wA,
    bf16* __restrict__ y, float* __restrict__ ssum, float* __restrict__ ssq)
{
    __shared__ __align__(16) bf16 Aw[2 * AW_BUF];   // 74,880 B
    __shared__ float wgs[8], wgq[8];

    int tid  = threadIdx.x;
    int wid  = tid >> 6;            // 0..4
    int lane = tid & 63;
    int n = lane & 15, q = lane >> 4;

    int bid = blockIdx.x;           // 8b * 4ct * 16rt = 512
    int b   = bid >> 6;
    int rem = bid & 63;
    int ct  = rem >> 4;
    int rt  = rem & 15;
    int co0 = ct * 64, h0 = rt * 5;

    if (tid < 8) { wgs[tid] = 0.0f; wgq[tid] = 0.0f; }

    f32x4 acc[4][5];
    #pragma unroll
    for (int i = 0; i < 4; i++)
        #pragma unroll
        for (int j = 0; j < 5; j++) acc[i][j] = (f32x4){0.f, 0.f, 0.f, 0.f};

    // stage Aw chunk 0 into buffer 0
    for (int p = wid; p < 36; p += 5) {
        int tap = p >> 2, qq = p & 3;
        glds16((const char*)(wA + ((size_t)(0 * 36 + p) * 256 + co0) * 8) + lane * 16,
               (char*)(Aw + tap * AW_T + qq * AW_Q) + lane * 16);
    }

    for (int c = 0; c < 8; c++) {
        __syncthreads();            // Aw chunk c landed (barrier drains vmcnt)
        // prefetch next chunk's weights into the other buffer
        if (c + 1 < 8) {
            bf16* dst = Aw + (((c + 1) & 1) ? AW_BUF : 0);
            for (int p = wid; p < 36; p += 5) {
                int tap = p >> 2, qq = p & 3;
                glds16((const char*)(wA + ((size_t)((c + 1) * 36 + p) * 256 + co0) * 8) + lane * 16,
                       (char*)(dst + tap * AW_T + qq * AW_Q) + lane * 16);
            }
        }
        const bf16* awc = Aw + ((c & 1) ? AW_BUF : 0) + q * AW_Q + n * 8;
        // B row base for this wave/chunk: plane (b, c*4+q), row h0+wid
        const bf16* xq = xp + (((size_t)(b * 32 + c * 4 + q) * 82 + (h0 + wid)) * 82) * 8 + n * 8;

        #pragma unroll
        for (int tap = 0; tap < 9; tap++) {
            const int r = tap / 3, s = tap - 3 * r;
            bf16x8 af[4], bfr[5];
            #pragma unroll
            for (int mt = 0; mt < 4; mt++)
                af[mt] = *(const bf16x8*)(awc + tap * AW_T + mt * 128);
            #pragma unroll
            for (int nt = 0; nt < 5; nt++)
                bfr[nt] = *(const bf16x8*)(xq + (r * 82 + s + nt * 16) * 8);
            #pragma unroll
            for (int mt = 0; mt < 4; mt++)
                #pragma unroll
                for (int nt = 0; nt < 5; nt++)
                    acc[mt][nt] = __builtin_amdgcn_mfma_f32_16x16x32_bf16(
                        af[mt], bfr[nt], acc[mt][nt], 0, 0, 0);
        }
    }

    // epilogue: store y (chunked bf16) + group stats
    int h = h0 + wid;
    #pragma unroll
    for (int mt = 0; mt < 4; mt++) {
        float s1 = 0.0f, s2 = 0.0f;
        int co  = co0 + mt * 16 + q * 4;
        int cib = co >> 3, c8 = co & 7;
        #pragma unroll
        for (int nt = 0; nt < 5; nt++) {
            int col = nt * 16 + n;
            bf16x4 pk;
            #pragma unroll
            for (int rg = 0; rg < 4; rg++) {
                float v = acc[mt][nt][rg];
                pk[rg] = (bf16)v;
                s1 += v;
                s2 = fmaf(v, v, s2);
            }
            *(bf16x4*)(y + ((((size_t)(b * 32 + cib) * 80 + h) * 80 + col) * 8 + c8)) = pk;
        }
        #pragma unroll
        for (int off = 1; off < 16; off <<= 1) {
            s1 += __shfl_xor(s1, off, 64);
            s2 += __shfl_xor(s2, off, 64);
        }
        if (n == 0) {
            int gl = mt * 2 + (q >> 1);
            atomicAdd(&wgs[gl], s1);
            atomicAdd(&wgq[gl], s2);
        }
    }
    __syncthreads();
    if (tid < 8) {
        atomicAdd(&ssum[b * 32 + ct * 8 + tid], wgs[tid]);
        atomicAdd(&ssq [b * 32 + ct * 8 + tid], wgq[tid]);
    }
}

// ---------------- finalize stats ----------------
__global__ void statfin_kernel(const float* __restrict__ s, const float* __restrict__ sq,
                               float* __restrict__ mu, float* __restrict__ rs)
{
    int i = threadIdx.x;
    const float cnt = (float)(8 * NHW);
    float m = s[i] / cnt;
    float v = sq[i] / cnt - m * m;
    mu[i] = m;
    rs[i] = rsqrtf(v + GN_EPS);
}

// ---------------- prep2: y1 -> GN1+ReLU -> xp interior --------------------------
__global__ __launch_bounds__(256) void prep2_kernel(
    const bf16* __restrict__ y, bf16* __restrict__ xp,
    const float* __restrict__ mu, const float* __restrict__ rs,
    const float* __restrict__ gamma, const float* __restrict__ beta)
{
    int bid = blockIdx.x;
    int b = bid / 640; int rem = bid - b * 640;
    int cib = rem / 20; int rq = rem - cib * 20;
    int gidx = b * 32 + cib;
    float m = mu[gidx], r = rs[gidx];
    const bf16* src = y + (size_t)(b * 32 + cib) * 51200 + rq * 2560;
    for (int u = threadIdx.x; u < 1280; u += 256) {
        int e = 2 * u;
        int row = rq * 4 + e / 640;
        int w640 = e % 640;
        int c8 = e & 7;
        int c = cib * 8 + c8;
        float sc0 = r * gamma[c],     sh0 = beta[c]     - m * sc0;
        float sc1 = r * gamma[c + 1], sh1 = beta[c + 1] - m * sc1;
        bf16x2 iv = *(const bf16x2*)(src + e);
        bf16x2 pk = { (bf16)fmaxf(fmaf((float)iv[0], sc0, sh0), 0.0f),
                      (bf16)fmaxf(fmaf((float)iv[1], sc1, sh1), 0.0f) };
        size_t xidx = (((size_t)(b * 32 + cib) * 82 + row + 1) * 82) * 8 + 8 + w640;
        *(bf16x2*)(xp + xidx) = pk;
    }
}

// ---------------- final: out = relu(gn2(y2) * gate + x), NCHW f32 ---------------
__global__ __launch_bounds__(256) void final_kernel(
    const bf16* __restrict__ y, const float* __restrict__ x,
    const float* __restrict__ gate,
    const float* __restrict__ mu, const float* __restrict__ rs,
    const float* __restrict__ gamma, const float* __restrict__ beta,
    float* __restrict__ out)
{
    __shared__ float lds[8 * 324];
    int bid = blockIdx.x;
    int b = bid / 640; int rem = bid - b * 640;
    int cib = rem / 20; int rq = rem - cib * 20;
    int gidx = b * 32 + cib;
    float m = mu[gidx], r = rs[gidx];
    const bf16* src = y + (size_t)(b * 32 + cib) * 51200 + rq * 2560;
    for (int u = threadIdx.x; u < 1280; u += 256) {
        int e = 2 * u;
        int c8 = e & 7;
        int rc = e >> 3;
        int c = cib * 8 + c8;
        float sc0 = r * gamma[c],     sh0 = beta[c]     - m * sc0;
        float sc1 = r * gamma[c + 1], sh1 = beta[c + 1] - m * sc1;
        bf16x2 iv = *(const bf16x2*)(src + e);
        lds[c8 * 324 + rc]       = fmaf((float)iv[0], sc0, sh0);
        lds[(c8 + 1) * 324 + rc] = fmaf((float)iv[1], sc1, sh1);
    }
    __syncthreads();
    const float* gp = gate + b * NHW + rq * 320;
    for (int e2 = threadIdx.x; e2 < 2560; e2 += 256) {
        int c8 = e2 / 320, rc = e2 - c8 * 320;
        int c = cib * 8 + c8;
        size_t oidx = (size_t)(b * NC + c) * NHW + rq * 320 + rc;
        float v = fmaf(lds[c8 * 324 + rc], gp[rc], x[oidx]);
        out[oidx] = fmaxf(v, 0.0f);
    }
}

extern "C" void kernel_launch(void* const* d_in, const int* in_sizes, int n_in,
                              void* d_out, int out_size, void* d_ws, size_t ws_size,
                              hipStream_t stream)
{
    const float* x     = (const float*)d_in[0];
    const float* w1    = (const float*)d_in[1];
    const float* gn1_w = (const float*)d_in[2];
    const float* gn1_b = (const float*)d_in[3];
    const float* w2    = (const float*)d_in[4];
    const float* gn2_w = (const float*)d_in[5];
    const float* gn2_b = (const float*)d_in[6];
    const float* gw    = (const float*)d_in[7];
    const float* gb    = (const float*)d_in[8];

    // d_out (52.4 MB): xp scratch 27.54 MB | gpart scratch 6.55 MB | (final writes all)
    bf16*  xp    = (bf16*)d_out;
    float* gpart = (float*)((char*)d_out + 27541504);
    float* out   = (float*)d_out;

    char* wsb = (char*)d_ws;
    bf16*  y     = (bf16*)wsb;                                   // 26,214,400 B
    float* gate  = (float*)(wsb + 26214400);                     //    204,800 B
    bf16*  wA1   = (bf16*)(wsb + 26214400 + 204800);             //  1,179,648 B
    bf16*  wA2   = wA1 + 589824;                                 //  1,179,648 B
    float* stats = (float*)(wsb + 26214400 + 204800 + 2 * 1179648);
    float* s1  = stats,        * s1q = stats + 256;
    float* mu1 = stats + 512,  * rs1 = stats + 768;
    float* s2  = stats + 1024, * s2q = stats + 1280;
    float* mu2 = stats + 1536, * rs2 = stats + 1792;

    setup_kernel<<<4609, 256, 0, stream>>>(w1, w2, wA1, wA2, stats);
    prep1_kernel<<<20480, 256, 0, stream>>>(x, xp, gw, gpart);
    gate_fin_kernel<<<200, 256, 0, stream>>>(gpart, gb, gate);
    conv_kernel<<<512, 320, 0, stream>>>(xp, wA1, y, s1, s1q);
    statfin_kernel<<<1, 256, 0, stream>>>(s1, s1q, mu1, rs1);
    prep2_kernel<<<5120, 256, 0, stream>>>(y, xp, mu1, rs1, gn1_w, gn1_b);
    conv_kernel<<<512, 320, 0, stream>>>(xp, wA2, y, s2, s2q);
    statfin_kernel<<<1, 256, 0, stream>>>(s2, s2q, mu2, rs2);
    final_kernel<<<5120, 256, 0, stream>>>(y, x, gate, mu2, rs2, gn2_w, gn2_b, out);
}

// Round 5
// 315.396 us; speedup vs baseline: 1.0460x; 1.0460x over previous
//
#include <hip/hip_runtime.h>
#include <math.h>

#define NB   8
#define NC   256
#define NH   80
#define NW   80
#define NHW  6400
#define GN_EPS 1e-5f

typedef __bf16 bf16;
typedef bf16 bf16x2 __attribute__((ext_vector_type(2)));
typedef bf16 bf16x4 __attribute__((ext_vector_type(4)));
typedef bf16 bf16x8 __attribute__((ext_vector_type(8)));
typedef float f32x4 __attribute__((ext_vector_type(4)));

typedef __attribute__((address_space(1))) void gvoid;
typedef __attribute__((address_space(3))) void lvoid;
__device__ __forceinline__ void glds16(const void* g, void* l) {
    __builtin_amdgcn_global_load_lds((const gvoid*)g, (lvoid*)l, 16, 0, 0);
}

// Aw: [9 tap][4 qq] qq stride 520 elems (1040 B -> bank offset +4)
#define AW_Q 520
#define AW_T 2080
#define AW_BUF 18720   // 9 * 2080 elems per buffer (37440 B)

// ---------------- setup: zero stats, repack both weight tensors ------------------
// wA layout: [chunk(8)][tap(9)][qq(4)][co(256)][c8(8)] bf16
__global__ __launch_bounds__(256) void setup_kernel(
    const float* __restrict__ w1, const float* __restrict__ w2,
    bf16* __restrict__ wA1, bf16* __restrict__ wA2,
    float* __restrict__ stats)
{
    int blk = blockIdx.x, tid = threadIdx.x;
    if (blk == 0) {
        #pragma unroll
        for (int k = 0; k < 8; k++) stats[tid + k * 256] = 0.0f;
        return;
    }
    int rb = blk - 1;                            // 0..4607
    const float* w = (rb < 2304) ? w1 : w2;
    bf16* wA       = (rb < 2304) ? wA1 : wA2;
    int idx = (rb % 2304) * 256 + tid;
    int c8 = idx & 7;
    int co = (idx >> 3) & 255;
    int qq = (idx >> 11) & 3;
    int tc = idx >> 13;                          // 0..71
    int tap = tc % 9, chunk = tc / 9;
    int ci = chunk * 32 + qq * 8 + c8;
    wA[idx] = (bf16)w[(size_t)(co * 256 + ci) * 9 + tap];
}

// ---------------- prep1: x NCHW f32 -> xp[b][cib][82][82][8] bf16 + halo + gate part
__global__ __launch_bounds__(256) void prep1_kernel(
    const float* __restrict__ x, bf16* __restrict__ xp,
    const float* __restrict__ gw, float* __restrict__ gpart)
{
    __shared__ float tile[8 * 84];
    int bid = blockIdx.x;
    int row = bid % 80;
    int cib = (bid / 80) & 31;
    int b   = bid / 2560;
    for (int e = threadIdx.x; e < 640; e += 256) {
        int c8 = e / 80, col = e - c8 * 80;
        tile[c8 * 84 + col] = x[((size_t)(b * NC + cib * 8 + c8) * NH + row) * NW + col];
    }
    __syncthreads();
    // interior pack
    size_t base = (((size_t)(b * 32 + cib) * 82 + row + 1) * 82) * 8 + 8;
    for (int t = threadIdx.x; t < 320; t += 256) {
        int e = 2 * t, col = e >> 3, c8 = e & 7;
        bf16x2 pk = { (bf16)tile[c8 * 84 + col], (bf16)tile[(c8 + 1) * 84 + col] };
        *(bf16x2*)(xp + base + e) = pk;
    }
    // gate partial over this block's 8 channels -> per-cib slice (no atomics)
    if (threadIdx.x < 80) {
        int col = threadIdx.x;
        float s = 0.0f;
        #pragma unroll
        for (int c8 = 0; c8 < 8; c8++) s = fmaf(tile[c8 * 84 + col], gw[cib * 8 + c8], s);
        gpart[((size_t)cib * NB + b) * NHW + row * 80 + col] = s;
    }
    // halo zeroing
    const uint4 z4 = make_uint4(0u, 0u, 0u, 0u);
    size_t img = ((size_t)(b * 32 + cib)) * 82;
    if (threadIdx.x < 2) {
        int col = threadIdx.x * 81;
        *(uint4*)(xp + ((img + row + 1) * 82 + col) * 8) = z4;
    }
    if (row == 0 || row == 79) {
        int prow = (row == 0) ? 0 : 81;
        for (int u = threadIdx.x; u < 82; u += 256)
            *(uint4*)(xp + ((img + prow) * 82 + u) * 8) = z4;
    }
}

// ---------------- conv: implicit GEMM; A via dbuf LDS, B direct global, row-batched
// block = 64co x 5rows x 80px, 5 waves (wave = one output row)
__global__ __launch_bounds__(320, 3) void conv_kernel(
    const bf16* __restrict__ xp, const bf16* __restrict__ wA,
    bf16* __restrict__ y, float* __restrict__ ssum, float* __restrict__ ssq)
{
    __shared__ __align__(16) bf16 Aw[2 * AW_BUF];   // 74,880 B
    __shared__ float wgs[8], wgq[8];

    int tid  = threadIdx.x;
    int wid  = tid >> 6;            // 0..4
    int lane = tid & 63;
    int n = lane & 15, q = lane >> 4;

    int bid = blockIdx.x;           // 8b * 4ct * 16rt = 512
    int b   = bid >> 6;
    int rem = bid & 63;
    int ct  = rem >> 4;
    int rt  = rem & 15;
    int co0 = ct * 64, h0 = rt * 5;

    if (tid < 8) { wgs[tid] = 0.0f; wgq[tid] = 0.0f; }

    f32x4 acc[4][5];
    #pragma unroll
    for (int i = 0; i < 4; i++)
        #pragma unroll
        for (int j = 0; j < 5; j++) acc[i][j] = (f32x4){0.f, 0.f, 0.f, 0.f};

    // stage Aw chunk 0 into buffer 0
    for (int p = wid; p < 36; p += 5) {
        int tap = p >> 2, qq = p & 3;
        glds16((const char*)(wA + ((size_t)p * 256 + co0) * 8) + lane * 16,
               (char*)(Aw + tap * AW_T + qq * AW_Q) + lane * 16);
    }

    for (int c = 0; c < 8; c++) {
        __syncthreads();            // Aw chunk c landed
        // prefetch next chunk's weights into the other buffer
        if (c + 1 < 8) {
            bf16* dst = Aw + (((c + 1) & 1) ? AW_BUF : 0);
            for (int p = wid; p < 36; p += 5) {
                int tap = p >> 2, qq = p & 3;
                glds16((const char*)(wA + ((size_t)((c + 1) * 36 + p) * 256 + co0) * 8) + lane * 16,
                       (char*)(dst + tap * AW_T + qq * AW_Q) + lane * 16);
            }
        }
        const bf16* awc = Aw + ((c & 1) ? AW_BUF : 0) + q * AW_Q + n * 8;
        const bf16* xq = xp + (((size_t)(b * 32 + c * 4 + q) * 82 + (h0 + wid)) * 82) * 8 + n * 8;

        #pragma unroll
        for (int r = 0; r < 3; r++) {
            // load the full row window for this r: 15 x 16B per lane
            bf16x8 L[15];
            #pragma unroll
            for (int nt = 0; nt < 5; nt++)
                #pragma unroll
                for (int s = 0; s < 3; s++)
                    L[nt * 3 + s] = *(const bf16x8*)(xq + (r * 82 + s + nt * 16) * 8);
            #pragma unroll
            for (int s = 0; s < 3; s++) {
                bf16x8 af[4];
                #pragma unroll
                for (int mt = 0; mt < 4; mt++)
                    af[mt] = *(const bf16x8*)(awc + (r * 3 + s) * AW_T + mt * 128);
                #pragma unroll
                for (int mt = 0; mt < 4; mt++)
                    #pragma unroll
                    for (int nt = 0; nt < 5; nt++)
                        acc[mt][nt] = __builtin_amdgcn_mfma_f32_16x16x32_bf16(
                            af[mt], L[nt * 3 + s], acc[mt][nt], 0, 0, 0);
            }
        }
    }

    // epilogue: store y (chunked bf16) + group stats
    int h = h0 + wid;
    #pragma unroll
    for (int mt = 0; mt < 4; mt++) {
        float s1 = 0.0f, s2 = 0.0f;
        int co  = co0 + mt * 16 + q * 4;
        int cib = co >> 3, c8 = co & 7;
        #pragma unroll
        for (int nt = 0; nt < 5; nt++) {
            int col = nt * 16 + n;
            bf16x4 pk;
            #pragma unroll
            for (int rg = 0; rg < 4; rg++) {
                float v = acc[mt][nt][rg];
                pk[rg] = (bf16)v;
                s1 += v;
                s2 = fmaf(v, v, s2);
            }
            *(bf16x4*)(y + ((((size_t)(b * 32 + cib) * 80 + h) * 80 + col) * 8 + c8)) = pk;
        }
        #pragma unroll
        for (int off = 1; off < 16; off <<= 1) {
            s1 += __shfl_xor(s1, off, 64);
            s2 += __shfl_xor(s2, off, 64);
        }
        if (n == 0) {
            int gl = mt * 2 + (q >> 1);
            atomicAdd(&wgs[gl], s1);
            atomicAdd(&wgq[gl], s2);
        }
    }
    __syncthreads();
    if (tid < 8) {
        atomicAdd(&ssum[b * 32 + ct * 8 + tid], wgs[tid]);
        atomicAdd(&ssq [b * 32 + ct * 8 + tid], wgq[tid]);
    }
}

// ---------------- prep2: y1 -> GN1+ReLU -> xp interior; tail blocks finalize gate -
__global__ __launch_bounds__(256) void prep2_kernel(
    const bf16* __restrict__ y, bf16* __restrict__ xp,
    const float* __restrict__ s, const float* __restrict__ sq,
    const float* __restrict__ gamma, const float* __restrict__ beta,
    const float* __restrict__ gpart, const float* __restrict__ gb,
    float* __restrict__ gate)
{
    int bid = blockIdx.x;
    if (bid >= 5120) {               // gate finalize duty: 200 blocks
        int i = (bid - 5120) * 256 + threadIdx.x;
        float gs = gb[0];
        #pragma unroll 8
        for (int k = 0; k < 32; k++) gs += gpart[(size_t)k * (NB * NHW) + i];
        gate[i] = fmaxf(tanhf(gs), 0.0f);
        return;
    }
    int b = bid / 640; int rem = bid - b * 640;
    int cib = rem / 20; int rq = rem - cib * 20;
    int gidx = b * 32 + cib;
    const float cnt = (float)(8 * NHW);
    float m  = s[gidx] / cnt;
    float vv = sq[gidx] / cnt - m * m;
    float r  = rsqrtf(vv + GN_EPS);
    const bf16* src = y + (size_t)(b * 32 + cib) * 51200 + rq * 2560;
    for (int u = threadIdx.x; u < 1280; u += 256) {
        int e = 2 * u;
        int row = rq * 4 + e / 640;
        int w640 = e % 640;
        int c8 = e & 7;
        int c = cib * 8 + c8;
        float sc0 = r * gamma[c],     sh0 = beta[c]     - m * sc0;
        float sc1 = r * gamma[c + 1], sh1 = beta[c + 1] - m * sc1;
        bf16x2 iv = *(const bf16x2*)(src + e);
        bf16x2 pk = { (bf16)fmaxf(fmaf((float)iv[0], sc0, sh0), 0.0f),
                      (bf16)fmaxf(fmaf((float)iv[1], sc1, sh1), 0.0f) };
        size_t xidx = (((size_t)(b * 32 + cib) * 82 + row + 1) * 82) * 8 + 8 + w640;
        *(bf16x2*)(xp + xidx) = pk;
    }
}

// ---------------- final: out = relu(gn2(y2) * gate + x), NCHW f32 ---------------
__global__ __launch_bounds__(256) void final_kernel(
    const bf16* __restrict__ y, const float* __restrict__ x,
    const float* __restrict__ gate,
    const float* __restrict__ s, const float* __restrict__ sq,
    const float* __restrict__ gamma, const float* __restrict__ beta,
    float* __restrict__ out)
{
    __shared__ float lds[8 * 324];
    int bid = blockIdx.x;
    int b = bid / 640; int rem = bid - b * 640;
    int cib = rem / 20; int rq = rem - cib * 20;
    int gidx = b * 32 + cib;
    const float cnt = (float)(8 * NHW);
    float m  = s[gidx] / cnt;
    float vv = sq[gidx] / cnt - m * m;
    float r  = rsqrtf(vv + GN_EPS);
    const bf16* src = y + (size_t)(b * 32 + cib) * 51200 + rq * 2560;
    for (int u = threadIdx.x; u < 1280; u += 256) {
        int e = 2 * u;
        int c8 = e & 7;
        int rc = e >> 3;
        int c = cib * 8 + c8;
        float sc0 = r * gamma[c],     sh0 = beta[c]     - m * sc0;
        float sc1 = r * gamma[c + 1], sh1 = beta[c + 1] - m * sc1;
        bf16x2 iv = *(const bf16x2*)(src + e);
        lds[c8 * 324 + rc]       = fmaf((float)iv[0], sc0, sh0);
        lds[(c8 + 1) * 324 + rc] = fmaf((float)iv[1], sc1, sh1);
    }
    __syncthreads();
    const float* gp = gate + b * NHW + rq * 320;
    for (int e2 = threadIdx.x; e2 < 2560; e2 += 256) {
        int c8 = e2 / 320, rc = e2 - c8 * 320;
        int c = cib * 8 + c8;
        size_t oidx = (size_t)(b * NC + c) * NHW + rq * 320 + rc;
        float v = fmaf(lds[c8 * 324 + rc], gp[rc], x[oidx]);
        out[oidx] = fmaxf(v, 0.0f);
    }
}

extern "C" void kernel_launch(void* const* d_in, const int* in_sizes, int n_in,
                              void* d_out, int out_size, void* d_ws, size_t ws_size,
                              hipStream_t stream)
{
    const float* x     = (const float*)d_in[0];
    const float* w1    = (const float*)d_in[1];
    const float* gn1_w = (const float*)d_in[2];
    const float* gn1_b = (const float*)d_in[3];
    const float* w2    = (const float*)d_in[4];
    const float* gn2_w = (const float*)d_in[5];
    const float* gn2_b = (const float*)d_in[6];
    const float* gw    = (const float*)d_in[7];
    const float* gb    = (const float*)d_in[8];

    // d_out (52.4 MB): xp scratch 27.54 MB | gpart scratch 6.55 MB | (final writes all)
    bf16*  xp    = (bf16*)d_out;
    float* gpart = (float*)((char*)d_out + 27541504);
    float* out   = (float*)d_out;

    char* wsb = (char*)d_ws;
    bf16*  y     = (bf16*)wsb;                                   // 26,214,400 B
    float* gate  = (float*)(wsb + 26214400);                     //    204,800 B
    bf16*  wA1   = (bf16*)(wsb + 26214400 + 204800);             //  1,179,648 B
    bf16*  wA2   = wA1 + 589824;                                 //  1,179,648 B
    float* stats = (float*)(wsb + 26214400 + 204800 + 2 * 1179648);
    float* s1  = stats,        * s1q = stats + 256;
    float* s2  = stats + 1024, * s2q = stats + 1280;

    setup_kernel<<<4609, 256, 0, stream>>>(w1, w2, wA1, wA2, stats);
    prep1_kernel<<<20480, 256, 0, stream>>>(x, xp, gw, gpart);
    conv_kernel<<<512, 320, 0, stream>>>(xp, wA1, y, s1, s1q);
    prep2_kernel<<<5320, 256, 0, stream>>>(y, xp, s1, s1q, gn1_w, gn1_b, gpart, gb, gate);
    conv_kernel<<<512, 320, 0, stream>>>(xp, wA2, y, s2, s2q);
    final_kernel<<<5120, 256, 0, stream>>>(y, x, gate, s2, s2q, gn2_w, gn2_b, out);
}

// Round 6
// 308.166 us; speedup vs baseline: 1.0705x; 1.0235x over previous
//
#include <hip/hip_runtime.h>
#include <math.h>

#define NB   8
#define NC   256
#define NH   80
#define NW   80
#define NHW  6400
#define GN_EPS 1e-5f

typedef __bf16 bf16;
typedef bf16 bf16x2 __attribute__((ext_vector_type(2)));
typedef bf16 bf16x4 __attribute__((ext_vector_type(4)));
typedef bf16 bf16x8 __attribute__((ext_vector_type(8)));
typedef float f32x4 __attribute__((ext_vector_type(4)));

typedef __attribute__((address_space(1))) void gvoid;
typedef __attribute__((address_space(3))) void lvoid;
__device__ __forceinline__ void glds16(const void* g, void* l) {
    __builtin_amdgcn_global_load_lds((const gvoid*)g, (lvoid*)l, 16, 0, 0);
}

// Aw: [9 tap][4 qq] qq stride 520 elems (1040 B -> bank offset +4)
#define AW_Q 520
#define AW_T 2080
#define AW_BUF 18720   // 9 * 2080 elems per buffer (37440 B)

// ---------------- prep: x -> xp (bf16, padded, ci-chunked) + gate partials;
//                  tail blocks: zero stats + repack weights -------------------
__global__ __launch_bounds__(256) void prep_kernel(
    const float* __restrict__ x, bf16* __restrict__ xp,
    const float* __restrict__ gw, float* __restrict__ gpart,
    const float* __restrict__ w1, const float* __restrict__ w2,
    bf16* __restrict__ wA1, bf16* __restrict__ wA2, float* __restrict__ stats)
{
    int bid = blockIdx.x;
    int tid = threadIdx.x;
    if (bid >= 20480) {                          // setup duty: 4609 blocks
        int blk = bid - 20480;
        if (blk == 0) {
            #pragma unroll
            for (int k = 0; k < 8; k++) stats[tid + k * 256] = 0.0f;
            return;
        }
        int rb = blk - 1;                        // 0..4607
        const float* w = (rb < 2304) ? w1 : w2;
        bf16* wA       = (rb < 2304) ? wA1 : wA2;
        int idx = (rb % 2304) * 256 + tid;
        int c8 = idx & 7;
        int co = (idx >> 3) & 255;
        int qq = (idx >> 11) & 3;
        int tc = idx >> 13;                      // 0..71
        int tap = tc % 9, chunk = tc / 9;
        int ci = chunk * 32 + qq * 8 + c8;
        wA[idx] = (bf16)w[(size_t)(co * 256 + ci) * 9 + tap];
        return;
    }
    __shared__ float tile[8 * 84];
    int row = bid % 80;
    int cib = (bid / 80) & 31;
    int b   = bid / 2560;
    for (int e = tid; e < 640; e += 256) {
        int c8 = e / 80, col = e - c8 * 80;
        tile[c8 * 84 + col] = x[((size_t)(b * NC + cib * 8 + c8) * NH + row) * NW + col];
    }
    __syncthreads();
    // interior pack
    size_t base = (((size_t)(b * 32 + cib) * 82 + row + 1) * 82) * 8 + 8;
    for (int t = tid; t < 320; t += 256) {
        int e = 2 * t, col = e >> 3, c8 = e & 7;
        bf16x2 pk = { (bf16)tile[c8 * 84 + col], (bf16)tile[(c8 + 1) * 84 + col] };
        *(bf16x2*)(xp + base + e) = pk;
    }
    // gate partial over this block's 8 channels -> per-cib slice (no atomics)
    if (tid < 80) {
        int col = tid;
        float s = 0.0f;
        #pragma unroll
        for (int c8 = 0; c8 < 8; c8++) s = fmaf(tile[c8 * 84 + col], gw[cib * 8 + c8], s);
        gpart[((size_t)cib * NB + b) * NHW + row * 80 + col] = s;
    }
    // halo zeroing
    const uint4 z4 = make_uint4(0u, 0u, 0u, 0u);
    size_t img = ((size_t)(b * 32 + cib)) * 82;
    if (tid < 2) {
        int col = tid * 81;
        *(uint4*)(xp + ((img + row + 1) * 82 + col) * 8) = z4;
    }
    if (row == 0 || row == 79) {
        int prow = (row == 0) ? 0 : 81;
        for (int u = tid; u < 82; u += 256)
            *(uint4*)(xp + ((img + prow) * 82 + u) * 8) = z4;
    }
}

// ---------------- conv: implicit GEMM; A via dbuf LDS, B direct global, L-dbuf --
// block = 64co x 4rows x 80px, 4 waves (wave = one output row), 256-reg budget
__global__ __launch_bounds__(256, 2) void conv_kernel(
    const bf16* __restrict__ xp, const bf16* __restrict__ wA,
    bf16* __restrict__ y, float* __restrict__ ssum, float* __restrict__ ssq)
{
    __shared__ __align__(16) bf16 Aw[2 * AW_BUF];   // 74,880 B
    __shared__ float wgs[8], wgq[8];

    int tid  = threadIdx.x;
    int wid  = tid >> 6;            // 0..3
    int lane = tid & 63;
    int n = lane & 15, q = lane >> 4;

    int bid = blockIdx.x;           // ct*160 + (b*20 + rt); ct-siblings same XCD
    int ct  = bid / 160;
    int t   = bid - ct * 160;
    int b   = t / 20;
    int rt  = t - b * 20;
    int co0 = ct * 64, h0 = rt * 4;

    if (tid < 8) { wgs[tid] = 0.0f; wgq[tid] = 0.0f; }

    f32x4 acc[4][5];
    #pragma unroll
    for (int i = 0; i < 4; i++)
        #pragma unroll
        for (int j = 0; j < 5; j++) acc[i][j] = (f32x4){0.f, 0.f, 0.f, 0.f};

    // stage Aw chunk 0 into buffer 0
    for (int p = wid; p < 36; p += 4) {
        int tap = p >> 2, qq = p & 3;
        glds16((const char*)(wA + ((size_t)p * 256 + co0) * 8) + lane * 16,
               (char*)(Aw + tap * AW_T + qq * AW_Q) + lane * 16);
    }

    for (int c = 0; c < 8; c++) {
        __syncthreads();            // Aw chunk c landed
        // prefetch next chunk's weights into the other buffer
        if (c + 1 < 8) {
            bf16* dst = Aw + (((c + 1) & 1) ? AW_BUF : 0);
            for (int p = wid; p < 36; p += 4) {
                int tap = p >> 2, qq = p & 3;
                glds16((const char*)(wA + ((size_t)((c + 1) * 36 + p) * 256 + co0) * 8) + lane * 16,
                       (char*)(dst + tap * AW_T + qq * AW_Q) + lane * 16);
            }
        }
        const bf16* awc = Aw + ((c & 1) ? AW_BUF : 0) + q * AW_Q + n * 8;
        const bf16* xq = xp + (((size_t)(b * 32 + c * 4 + q) * 82 + (h0 + wid)) * 82) * 8 + n * 8;

        // double-buffered row-window loads: 15 x 16B per lane per input row
        bf16x8 L[2][15];
        #pragma unroll
        for (int k = 0; k < 15; k++)
            L[0][k] = *(const bf16x8*)(xq + ((k / 3) * 16 + (k % 3)) * 8);
        #pragma unroll
        for (int r = 0; r < 3; r++) {
            if (r < 2) {
                #pragma unroll
                for (int k = 0; k < 15; k++)
                    L[(r + 1) & 1][k] =
                        *(const bf16x8*)(xq + ((r + 1) * 82 + (k / 3) * 16 + (k % 3)) * 8);
            }
            #pragma unroll
            for (int s = 0; s < 3; s++) {
                bf16x8 af[4];
                #pragma unroll
                for (int mt = 0; mt < 4; mt++)
                    af[mt] = *(const bf16x8*)(awc + (r * 3 + s) * AW_T + mt * 128);
                #pragma unroll
                for (int mt = 0; mt < 4; mt++)
                    #pragma unroll
                    for (int nt = 0; nt < 5; nt++)
                        acc[mt][nt] = __builtin_amdgcn_mfma_f32_16x16x32_bf16(
                            af[mt], L[r & 1][nt * 3 + s], acc[mt][nt], 0, 0, 0);
            }
        }
    }

    // epilogue: store y (chunked bf16) + group stats
    int h = h0 + wid;
    #pragma unroll
    for (int mt = 0; mt < 4; mt++) {
        float s1 = 0.0f, s2 = 0.0f;
        int co  = co0 + mt * 16 + q * 4;
        int cib = co >> 3, c8 = co & 7;
        #pragma unroll
        for (int nt = 0; nt < 5; nt++) {
            int col = nt * 16 + n;
            bf16x4 pk;
            #pragma unroll
            for (int rg = 0; rg < 4; rg++) {
                float v = acc[mt][nt][rg];
                pk[rg] = (bf16)v;
                s1 += v;
                s2 = fmaf(v, v, s2);
            }
            *(bf16x4*)(y + ((((size_t)(b * 32 + cib) * 80 + h) * 80 + col) * 8 + c8)) = pk;
        }
        #pragma unroll
        for (int off = 1; off < 16; off <<= 1) {
            s1 += __shfl_xor(s1, off, 64);
            s2 += __shfl_xor(s2, off, 64);
        }
        if (n == 0) {
            int gl = mt * 2 + (q >> 1);
            atomicAdd(&wgs[gl], s1);
            atomicAdd(&wgq[gl], s2);
        }
    }
    __syncthreads();
    if (tid < 8) {
        atomicAdd(&ssum[b * 32 + ct * 8 + tid], wgs[tid]);
        atomicAdd(&ssq [b * 32 + ct * 8 + tid], wgq[tid]);
    }
}

// ---------------- prep2: y1 -> GN1+ReLU -> xp interior; tail blocks finalize gate -
__global__ __launch_bounds__(256) void prep2_kernel(
    const bf16* __restrict__ y, bf16* __restrict__ xp,
    const float* __restrict__ s, const float* __restrict__ sq,
    const float* __restrict__ gamma, const float* __restrict__ beta,
    const float* __restrict__ gpart, const float* __restrict__ gb,
    float* __restrict__ gate)
{
    int bid = blockIdx.x;
    if (bid >= 5120) {               // gate finalize duty: 200 blocks
        int i = (bid - 5120) * 256 + threadIdx.x;
        float gs = gb[0];
        #pragma unroll 8
        for (int k = 0; k < 32; k++) gs += gpart[(size_t)k * (NB * NHW) + i];
        gate[i] = fmaxf(tanhf(gs), 0.0f);
        return;
    }
    int b = bid / 640; int rem = bid - b * 640;
    int cib = rem / 20; int rq = rem - cib * 20;
    int gidx = b * 32 + cib;
    const float cnt = (float)(8 * NHW);
    float m  = s[gidx] / cnt;
    float vv = sq[gidx] / cnt - m * m;
    float r  = rsqrtf(vv + GN_EPS);
    const bf16* src = y + (size_t)(b * 32 + cib) * 51200 + rq * 2560;
    for (int u = threadIdx.x; u < 1280; u += 256) {
        int e = 2 * u;
        int row = rq * 4 + e / 640;
        int w640 = e % 640;
        int c8 = e & 7;
        int c = cib * 8 + c8;
        float sc0 = r * gamma[c],     sh0 = beta[c]     - m * sc0;
        float sc1 = r * gamma[c + 1], sh1 = beta[c + 1] - m * sc1;
        bf16x2 iv = *(const bf16x2*)(src + e);
        bf16x2 pk = { (bf16)fmaxf(fmaf((float)iv[0], sc0, sh0), 0.0f),
                      (bf16)fmaxf(fmaf((float)iv[1], sc1, sh1), 0.0f) };
        size_t xidx = (((size_t)(b * 32 + cib) * 82 + row + 1) * 82) * 8 + 8 + w640;
        *(bf16x2*)(xp + xidx) = pk;
    }
}

// ---------------- final: out = relu(gn2(y2) * gate + x), NCHW f32 ---------------
__global__ __launch_bounds__(256) void final_kernel(
    const bf16* __restrict__ y, const float* __restrict__ x,
    const float* __restrict__ gate,
    const float* __restrict__ s, const float* __restrict__ sq,
    const float* __restrict__ gamma, const float* __restrict__ beta,
    float* __restrict__ out)
{
    __shared__ float lds[8 * 324];
    int bid = blockIdx.x;
    int b = bid / 640; int rem = bid - b * 640;
    int cib = rem / 20; int rq = rem - cib * 20;
    int gidx = b * 32 + cib;
    const float cnt = (float)(8 * NHW);
    float m  = s[gidx] / cnt;
    float vv = sq[gidx] / cnt - m * m;
    float r  = rsqrtf(vv + GN_EPS);
    const bf16* src = y + (size_t)(b * 32 + cib) * 51200 + rq * 2560;
    for (int u = threadIdx.x; u < 1280; u += 256) {
        int e = 2 * u;
        int c8 = e & 7;
        int rc = e >> 3;
        int c = cib * 8 + c8;
        float sc0 = r * gamma[c],     sh0 = beta[c]     - m * sc0;
        float sc1 = r * gamma[c + 1], sh1 = beta[c + 1] - m * sc1;
        bf16x2 iv = *(const bf16x2*)(src + e);
        lds[c8 * 324 + rc]       = fmaf((float)iv[0], sc0, sh0);
        lds[(c8 + 1) * 324 + rc] = fmaf((float)iv[1], sc1, sh1);
    }
    __syncthreads();
    const float* gp = gate + b * NHW + rq * 320;
    for (int e2 = threadIdx.x; e2 < 2560; e2 += 256) {
        int c8 = e2 / 320, rc = e2 - c8 * 320;
        int c = cib * 8 + c8;
        size_t oidx = (size_t)(b * NC + c) * NHW + rq * 320 + rc;
        float v = fmaf(lds[c8 * 324 + rc], gp[rc], x[oidx]);
        out[oidx] = fmaxf(v, 0.0f);
    }
}

extern "C" void kernel_launch(void* const* d_in, const int* in_sizes, int n_in,
                              void* d_out, int out_size, void* d_ws, size_t ws_size,
                              hipStream_t stream)
{
    const float* x     = (const float*)d_in[0];
    const float* w1    = (const float*)d_in[1];
    const float* gn1_w = (const float*)d_in[2];
    const float* gn1_b = (const float*)d_in[3];
    const float* w2    = (const float*)d_in[4];
    const float* gn2_w = (const float*)d_in[5];
    const float* gn2_b = (const float*)d_in[6];
    const float* gw    = (const float*)d_in[7];
    const float* gb    = (const float*)d_in[8];

    // d_out (52.4 MB): xp scratch 27.54 MB | gpart scratch 6.55 MB | (final writes all)
    bf16*  xp    = (bf16*)d_out;
    float* gpart = (float*)((char*)d_out + 27541504);
    float* out   = (float*)d_out;

    char* wsb = (char*)d_ws;
    bf16*  y     = (bf16*)wsb;                                   // 26,214,400 B
    float* gate  = (float*)(wsb + 26214400);                     //    204,800 B
    bf16*  wA1   = (bf16*)(wsb + 26214400 + 204800);             //  1,179,648 B
    bf16*  wA2   = wA1 + 589824;                                 //  1,179,648 B
    float* stats = (float*)(wsb + 26214400 + 204800 + 2 * 1179648);
    float* s1  = stats,        * s1q = stats + 256;
    float* s2  = stats + 1024, * s2q = stats + 1280;

    prep_kernel<<<25089, 256, 0, stream>>>(x, xp, gw, gpart, w1, w2, wA1, wA2, stats);
    conv_kernel<<<640, 256, 0, stream>>>(xp, wA1, y, s1, s1q);
    prep2_kernel<<<5320, 256, 0, stream>>>(y, xp, s1, s1q, gn1_w, gn1_b, gpart, gb, gate);
    conv_kernel<<<640, 256, 0, stream>>>(xp, wA2, y, s2, s2q);
    final_kernel<<<5120, 256, 0, stream>>>(y, x, gate, s2, s2q, gn2_w, gn2_b, out);
}

// Round 7
// 299.851 us; speedup vs baseline: 1.1002x; 1.0277x over previous
//
#include <hip/hip_runtime.h>
#include <math.h>

#define NB   8
#define NC   256
#define NH   80
#define NW   80
#define NHW  6400
#define GN_EPS 1e-5f

typedef __bf16 bf16;
typedef bf16 bf16x2 __attribute__((ext_vector_type(2)));
typedef bf16 bf16x4 __attribute__((ext_vector_type(4)));
typedef bf16 bf16x8 __attribute__((ext_vector_type(8)));
typedef float f32x4 __attribute__((ext_vector_type(4)));

typedef __attribute__((address_space(1))) void gvoid;
typedef __attribute__((address_space(3))) void lvoid;
__device__ __forceinline__ void glds16(const void* g, void* l) {
    __builtin_amdgcn_global_load_lds((const gvoid*)g, (lvoid*)l, 16, 0, 0);
}

// Aw: [9 tap][4 qq] qq stride 520 elems (1040 B -> bank offset +4)
#define AW_Q 520
#define AW_T 2080
#define AW_BUF 18720   // 9 * 2080 elems per buffer (37440 B)

// ---------------- prep: x -> xp (bf16, padded, ci-chunked), 4 rows/block,
//                  + gate partials; tail blocks: zero stats + repack weights ----
__global__ __launch_bounds__(256) void prep_kernel(
    const float* __restrict__ x, bf16* __restrict__ xp,
    const float* __restrict__ gw, float* __restrict__ gpart,
    const float* __restrict__ w1, const float* __restrict__ w2,
    bf16* __restrict__ wA1, bf16* __restrict__ wA2, float* __restrict__ stats)
{
    int bid = blockIdx.x;
    int tid = threadIdx.x;
    if (bid >= 5120) {                           // setup duty: 4609 blocks
        int blk = bid - 5120;
        if (blk == 0) {
            #pragma unroll
            for (int k = 0; k < 8; k++) stats[tid + k * 256] = 0.0f;
            return;
        }
        int rb = blk - 1;                        // 0..4607
        const float* w = (rb < 2304) ? w1 : w2;
        bf16* wA       = (rb < 2304) ? wA1 : wA2;
        int idx = (rb % 2304) * 256 + tid;
        int c8 = idx & 7;
        int co = (idx >> 3) & 255;
        int qq = (idx >> 11) & 3;
        int tc = idx >> 13;                      // 0..71
        int tap = tc % 9, chunk = tc / 9;
        int ci = chunk * 32 + qq * 8 + c8;
        wA[idx] = (bf16)w[(size_t)(co * 256 + ci) * 9 + tap];
        return;
    }
    __shared__ float tile[8][4][84];
    int rg  = bid % 20;                          // row group (4 rows)
    int cib = (bid / 20) & 31;
    int b   = bid / 640;
    for (int e = tid; e < 2560; e += 256) {
        int c8 = e / 320, r2 = e - c8 * 320;
        int rr = r2 / 80, col = r2 - rr * 80;
        tile[c8][rr][col] =
            x[((size_t)(b * NC + cib * 8 + c8) * NH + rg * 4 + rr) * NW + col];
    }
    __syncthreads();
    // interior pack (4 rows)
    for (int t = tid; t < 1280; t += 256) {
        int rr = t / 320, t2 = t - rr * 320;
        int e = 2 * t2, col = e >> 3, c8 = e & 7;
        bf16x2 pk = { (bf16)tile[c8][rr][col], (bf16)tile[c8 + 1][rr][col] };
        size_t base = (((size_t)(b * 32 + cib) * 82 + rg * 4 + rr + 1) * 82) * 8 + 8;
        *(bf16x2*)(xp + base + e) = pk;
    }
    // gate partials
    if (tid < 320) {
        int rr = tid / 80, col = tid - rr * 80;
        float s = 0.0f;
        #pragma unroll
        for (int c8 = 0; c8 < 8; c8++)
            s = fmaf(tile[c8][rr][col], gw[cib * 8 + c8], s);
        gpart[((size_t)cib * NB + b) * NHW + (rg * 4 + rr) * 80 + col] = s;
    }
    // halo zeroing
    const uint4 z4 = make_uint4(0u, 0u, 0u, 0u);
    size_t img = ((size_t)(b * 32 + cib)) * 82;
    if (tid < 8) {
        int rr = tid >> 1, col = (tid & 1) * 81;
        *(uint4*)(xp + ((img + rg * 4 + rr + 1) * 82 + col) * 8) = z4;
    }
    if (rg == 0 || rg == 19) {
        int prow = (rg == 0) ? 0 : 81;
        for (int u = tid; u < 82; u += 256)
            *(uint4*)(xp + ((img + prow) * 82 + u) * 8) = z4;
    }
}

// ---------------- conv: implicit GEMM; A via dbuf LDS, B global, FIFO-ordered ---
// block = 64co x 4rows x 80px, 4 waves (wave = one output row)
__global__ __launch_bounds__(256, 2) void conv_kernel(
    const bf16* __restrict__ xp, const bf16* __restrict__ wA,
    bf16* __restrict__ y, float* __restrict__ ssum, float* __restrict__ ssq)
{
    __shared__ __align__(16) bf16 Aw[2 * AW_BUF];   // 74,880 B
    __shared__ float wgs[8], wgq[8];

    int tid  = threadIdx.x;
    int wid  = tid >> 6;            // 0..3
    int lane = tid & 63;
    int n = lane & 15, q = lane >> 4;

    int bid = blockIdx.x;           // ct*160 + (b*20 + rt); ct-siblings same XCD
    int ct  = bid / 160;
    int t   = bid - ct * 160;
    int b   = t / 20;
    int rt  = t - b * 20;
    int co0 = ct * 64, h0 = rt * 4;

    if (tid < 8) { wgs[tid] = 0.0f; wgq[tid] = 0.0f; }

    f32x4 acc[4][5];
    #pragma unroll
    for (int i = 0; i < 4; i++)
        #pragma unroll
        for (int j = 0; j < 5; j++) acc[i][j] = (f32x4){0.f, 0.f, 0.f, 0.f};

    // stage Aw chunk 0 into buffer 0
    for (int p = wid; p < 36; p += 4) {
        int tap = p >> 2, qq = p & 3;
        glds16((const char*)(wA + ((size_t)p * 256 + co0) * 8) + lane * 16,
               (char*)(Aw + tap * AW_T + qq * AW_Q) + lane * 16);
    }

    for (int c = 0; c < 8; c++) {
        __syncthreads();            // Aw chunk c landed (full drain here is fine)
        const bf16* awc = Aw + ((c & 1) ? AW_BUF : 0) + q * AW_Q + n * 8;
        const bf16* xq  = xp + (((size_t)(b * 32 + c * 4 + q) * 82 + (h0 + wid)) * 82) * 8 + n * 8;

        bf16x8 L0[15], L1[15];
        // rows r=0, r=1: issue BEFORE anything else (oldest in vmcnt FIFO)
        #pragma unroll
        for (int k = 0; k < 15; k++)
            L0[k] = *(const bf16x8*)(xq + ((k / 3) * 16 + (k % 3)) * 8);
        #pragma unroll
        for (int k = 0; k < 15; k++)
            L1[k] = *(const bf16x8*)(xq + (82 + (k / 3) * 16 + (k % 3)) * 8);

        // r = 0 MFMAs (waits only on L0: r1 loads may remain outstanding)
        #pragma unroll
        for (int s = 0; s < 3; s++) {
            bf16x8 af[4];
            #pragma unroll
            for (int mt = 0; mt < 4; mt++)
                af[mt] = *(const bf16x8*)(awc + s * AW_T + mt * 128);
            #pragma unroll
            for (int mt = 0; mt < 4; mt++)
                #pragma unroll
                for (int nt = 0; nt < 5; nt++)
                    acc[mt][nt] = __builtin_amdgcn_mfma_f32_16x16x32_bf16(
                        af[mt], L0[nt * 3 + s], acc[mt][nt], 0, 0, 0);
        }
        // reload L0 with row r=2 — must issue BEFORE the glds prefetch
        #pragma unroll
        for (int k = 0; k < 15; k++)
            L0[k] = *(const bf16x8*)(xq + (164 + (k / 3) * 16 + (k % 3)) * 8);

        __builtin_amdgcn_sched_barrier(0);   // pin r2-loads above the glds

        // prefetch next chunk's weights (issued LAST: never blocks our MFMAs)
        if (c < 7) {
            bf16* dst = Aw + (((c + 1) & 1) ? AW_BUF : 0);
            for (int p = wid; p < 36; p += 4) {
                int tap = p >> 2, qq = p & 3;
                glds16((const char*)(wA + ((size_t)((c + 1) * 36 + p) * 256 + co0) * 8) + lane * 16,
                       (char*)(dst + tap * AW_T + qq * AW_Q) + lane * 16);
            }
        }

        // r = 1 MFMAs (vmcnt covers r2-loads + glds outstanding — no glds wait)
        #pragma unroll
        for (int s = 0; s < 3; s++) {
            bf16x8 af[4];
            #pragma unroll
            for (int mt = 0; mt < 4; mt++)
                af[mt] = *(const bf16x8*)(awc + (3 + s) * AW_T + mt * 128);
            #pragma unroll
            for (int mt = 0; mt < 4; mt++)
                #pragma unroll
                for (int nt = 0; nt < 5; nt++)
                    acc[mt][nt] = __builtin_amdgcn_mfma_f32_16x16x32_bf16(
                        af[mt], L1[nt * 3 + s], acc[mt][nt], 0, 0, 0);
        }
        // r = 2 MFMAs (waits r2-loads only; glds may stay outstanding)
        #pragma unroll
        for (int s = 0; s < 3; s++) {
            bf16x8 af[4];
            #pragma unroll
            for (int mt = 0; mt < 4; mt++)
                af[mt] = *(const bf16x8*)(awc + (6 + s) * AW_T + mt * 128);
            #pragma unroll
            for (int mt = 0; mt < 4; mt++)
                #pragma unroll
                for (int nt = 0; nt < 5; nt++)
                    acc[mt][nt] = __builtin_amdgcn_mfma_f32_16x16x32_bf16(
                        af[mt], L0[nt * 3 + s], acc[mt][nt], 0, 0, 0);
        }
    }

    // epilogue: store y (chunked bf16) + group stats
    int h = h0 + wid;
    #pragma unroll
    for (int mt = 0; mt < 4; mt++) {
        float s1 = 0.0f, s2 = 0.0f;
        int co  = co0 + mt * 16 + q * 4;
        int cib = co >> 3, c8 = co & 7;
        #pragma unroll
        for (int nt = 0; nt < 5; nt++) {
            int col = nt * 16 + n;
            bf16x4 pk;
            #pragma unroll
            for (int rg = 0; rg < 4; rg++) {
                float v = acc[mt][nt][rg];
                pk[rg] = (bf16)v;
                s1 += v;
                s2 = fmaf(v, v, s2);
            }
            *(bf16x4*)(y + ((((size_t)(b * 32 + cib) * 80 + h) * 80 + col) * 8 + c8)) = pk;
        }
        #pragma unroll
        for (int off = 1; off < 16; off <<= 1) {
            s1 += __shfl_xor(s1, off, 64);
            s2 += __shfl_xor(s2, off, 64);
        }
        if (n == 0) {
            int gl = mt * 2 + (q >> 1);
            atomicAdd(&wgs[gl], s1);
            atomicAdd(&wgq[gl], s2);
        }
    }
    __syncthreads();
    if (tid < 8) {
        atomicAdd(&ssum[b * 32 + ct * 8 + tid], wgs[tid]);
        atomicAdd(&ssq [b * 32 + ct * 8 + tid], wgq[tid]);
    }
}

// ---------------- prep2: y1 -> GN1+ReLU -> xp interior; tail blocks finalize gate -
__global__ __launch_bounds__(256) void prep2_kernel(
    const bf16* __restrict__ y, bf16* __restrict__ xp,
    const float* __restrict__ s, const float* __restrict__ sq,
    const float* __restrict__ gamma, const float* __restrict__ beta,
    const float* __restrict__ gpart, const float* __restrict__ gb,
    float* __restrict__ gate)
{
    int bid = blockIdx.x;
    if (bid >= 5120) {               // gate finalize duty: 200 blocks
        int i = (bid - 5120) * 256 + threadIdx.x;
        float gs = gb[0];
        #pragma unroll 8
        for (int k = 0; k < 32; k++) gs += gpart[(size_t)k * (NB * NHW) + i];
        gate[i] = fmaxf(tanhf(gs), 0.0f);
        return;
    }
    int b = bid / 640; int rem = bid - b * 640;
    int cib = rem / 20; int rq = rem - cib * 20;
    int gidx = b * 32 + cib;
    const float cnt = (float)(8 * NHW);
    float m  = s[gidx] / cnt;
    float vv = sq[gidx] / cnt - m * m;
    float r  = rsqrtf(vv + GN_EPS);
    const bf16* src = y + (size_t)(b * 32 + cib) * 51200 + rq * 2560;
    for (int u = threadIdx.x; u < 1280; u += 256) {
        int e = 2 * u;
        int row = rq * 4 + e / 640;
        int w640 = e % 640;
        int c8 = e & 7;
        int c = cib * 8 + c8;
        float sc0 = r * gamma[c],     sh0 = beta[c]     - m * sc0;
        float sc1 = r * gamma[c + 1], sh1 = beta[c + 1] - m * sc1;
        bf16x2 iv = *(const bf16x2*)(src + e);
        bf16x2 pk = { (bf16)fmaxf(fmaf((float)iv[0], sc0, sh0), 0.0f),
                      (bf16)fmaxf(fmaf((float)iv[1], sc1, sh1), 0.0f) };
        size_t xidx = (((size_t)(b * 32 + cib) * 82 + row + 1) * 82) * 8 + 8 + w640;
        *(bf16x2*)(xp + xidx) = pk;
    }
}

// ---------------- final: out = relu(gn2(y2) * gate + x), NCHW f32 ---------------
__global__ __launch_bounds__(256) void final_kernel(
    const bf16* __restrict__ y, const float* __restrict__ x,
    const float* __restrict__ gate,
    const float* __restrict__ s, const float* __restrict__ sq,
    const float* __restrict__ gamma, const float* __restrict__ beta,
    float* __restrict__ out)
{
    __shared__ float lds[8 * 324];
    int bid = blockIdx.x;
    int b = bid / 640; int rem = bid - b * 640;
    int cib = rem / 20; int rq = rem - cib * 20;
    int gidx = b * 32 + cib;
    const float cnt = (float)(8 * NHW);
    float m  = s[gidx] / cnt;
    float vv = sq[gidx] / cnt - m * m;
    float r  = rsqrtf(vv + GN_EPS);
    const bf16* src = y + (size_t)(b * 32 + cib) * 51200 + rq * 2560;
    for (int u = threadIdx.x; u < 1280; u += 256) {
        int e = 2 * u;
        int c8 = e & 7;
        int rc = e >> 3;
        int c = cib * 8 + c8;
        float sc0 = r * gamma[c],     sh0 = beta[c]     - m * sc0;
        float sc1 = r * gamma[c + 1], sh1 = beta[c + 1] - m * sc1;
        bf16x2 iv = *(const bf16x2*)(src + e);
        lds[c8 * 324 + rc]       = fmaf((float)iv[0], sc0, sh0);
        lds[(c8 + 1) * 324 + rc] = fmaf((float)iv[1], sc1, sh1);
    }
    __syncthreads();
    const float* gp = gate + b * NHW + rq * 320;
    for (int e2 = threadIdx.x; e2 < 2560; e2 += 256) {
        int c8 = e2 / 320, rc = e2 - c8 * 320;
        int c = cib * 8 + c8;
        size_t oidx = (size_t)(b * NC + c) * NHW + rq * 320 + rc;
        float v = fmaf(lds[c8 * 324 + rc], gp[rc], x[oidx]);
        out[oidx] = fmaxf(v, 0.0f);
    }
}

extern "C" void kernel_launch(void* const* d_in, const int* in_sizes, int n_in,
                              void* d_out, int out_size, void* d_ws, size_t ws_size,
                              hipStream_t stream)
{
    const float* x     = (const float*)d_in[0];
    const float* w1    = (const float*)d_in[1];
    const float* gn1_w = (const float*)d_in[2];
    const float* gn1_b = (const float*)d_in[3];
    const float* w2    = (const float*)d_in[4];
    const float* gn2_w = (const float*)d_in[5];
    const float* gn2_b = (const float*)d_in[6];
    const float* gw    = (const float*)d_in[7];
    const float* gb    = (const float*)d_in[8];

    // d_out (52.4 MB): xp scratch 27.54 MB | gpart scratch 6.55 MB | (final writes all)
    bf16*  xp    = (bf16*)d_out;
    float* gpart = (float*)((char*)d_out + 27541504);
    float* out   = (float*)d_out;

    char* wsb = (char*)d_ws;
    bf16*  y     = (bf16*)wsb;                                   // 26,214,400 B
    float* gate  = (float*)(wsb + 26214400);                     //    204,800 B
    bf16*  wA1   = (bf16*)(wsb + 26214400 + 204800);             //  1,179,648 B
    bf16*  wA2   = wA1 + 589824;                                 //  1,179,648 B
    float* stats = (float*)(wsb + 26214400 + 204800 + 2 * 1179648);
    float* s1  = stats,        * s1q = stats + 256;
    float* s2  = stats + 1024, * s2q = stats + 1280;

    prep_kernel<<<9729, 256, 0, stream>>>(x, xp, gw, gpart, w1, w2, wA1, wA2, stats);
    conv_kernel<<<640, 256, 0, stream>>>(xp, wA1, y, s1, s1q);
    prep2_kernel<<<5320, 256, 0, stream>>>(y, xp, s1, s1q, gn1_w, gn1_b, gpart, gb, gate);
    conv_kernel<<<640, 256, 0, stream>>>(xp, wA2, y, s2, s2q);
    final_kernel<<<5120, 256, 0, stream>>>(y, x, gate, s2, s2q, gn2_w, gn2_b, out);
}